// Round 1
// baseline (341.296 us; speedup 1.0000x reference)
//
#include <hip/hip_runtime.h>
#include <hip/hip_bf16.h>
#include <math.h>

#define T_TOK 2048
#define DM 768
#define DF 3072
#define NE 8

typedef __attribute__((ext_vector_type(4))) float f32x4;
typedef __attribute__((ext_vector_type(8))) short bf16x8;

static __device__ __forceinline__ ushort f2bf(float f) {
    union { float f; unsigned u; } x; x.f = f;
    unsigned r = x.u + 0x7fff + ((x.u >> 16) & 1);
    return (ushort)(r >> 16);
}
static __device__ __forceinline__ float bf2f(ushort u) {
    union { unsigned u; float f; } x; x.u = ((unsigned)u) << 16; return x.f;
}

// ---------------- LN + router (top-2) ----------------
__global__ __launch_bounds__(256) void ln_router_kernel(
    const float* __restrict__ hs, const float* __restrict__ gamma,
    const float* __restrict__ beta, const float* __restrict__ rw,
    ushort* __restrict__ xbf, float* __restrict__ topw, int* __restrict__ topi,
    int* __restrict__ counts)
{
    int t = blockIdx.x;
    int tid = threadIdx.x;
    const float* row = hs + (size_t)t * DM;
    float v[3];
    v[0] = row[tid]; v[1] = row[tid + 256]; v[2] = row[tid + 512];
    float s  = v[0] + v[1] + v[2];
    float sq = v[0]*v[0] + v[1]*v[1] + v[2]*v[2];
    #pragma unroll
    for (int off = 32; off > 0; off >>= 1) {
        s  += __shfl_down(s, off);
        sq += __shfl_down(sq, off);
    }
    __shared__ float wsum[4], wsq[4];
    __shared__ float pl[4][8];
    int lane = tid & 63, wv = tid >> 6;
    if (lane == 0) { wsum[wv] = s; wsq[wv] = sq; }
    __syncthreads();
    float tot  = wsum[0] + wsum[1] + wsum[2] + wsum[3];
    float totq = wsq[0] + wsq[1] + wsq[2] + wsq[3];
    float mu = tot * (1.0f / 768.0f);
    float var = totq * (1.0f / 768.0f) - mu * mu;
    float rstd = rsqrtf(var + 1e-5f);

    float p[8];
    #pragma unroll
    for (int e = 0; e < 8; e++) p[e] = 0.f;
    #pragma unroll
    for (int i = 0; i < 3; i++) {
        int d = tid + i * 256;
        float yv = (v[i] - mu) * rstd * gamma[d] + beta[d];
        xbf[(size_t)t * DM + d] = f2bf(yv);
        const float* r8 = rw + (size_t)d * 8;
        #pragma unroll
        for (int e = 0; e < 8; e++) p[e] += yv * r8[e];
    }
    #pragma unroll
    for (int off = 32; off > 0; off >>= 1) {
        #pragma unroll
        for (int e = 0; e < 8; e++) p[e] += __shfl_down(p[e], off);
    }
    if (lane == 0) {
        #pragma unroll
        for (int e = 0; e < 8; e++) pl[wv][e] = p[e];
    }
    __syncthreads();
    if (tid == 0) {
        float lg[8];
        #pragma unroll
        for (int e = 0; e < 8; e++) lg[e] = pl[0][e] + pl[1][e] + pl[2][e] + pl[3][e];
        int i0 = 0; float l0 = lg[0];
        #pragma unroll
        for (int e = 1; e < 8; e++) if (lg[e] > l0) { l0 = lg[e]; i0 = e; }
        int i1 = -1; float l1 = -3.4e38f;
        #pragma unroll
        for (int e = 0; e < 8; e++) if (e != i0 && lg[e] > l1) { l1 = lg[e]; i1 = e; }
        float w0 = 1.0f / (1.0f + __expf(l1 - l0));
        topi[2 * t] = i0;  topi[2 * t + 1] = i1;
        topw[2 * t] = w0;  topw[2 * t + 1] = 1.0f - w0;
        atomicAdd(&counts[i0], 1);
        atomicAdd(&counts[i1], 1);
    }
}

// ---------------- scan (prefix over 8 counts) ----------------
__global__ void scan_kernel(int* __restrict__ ctl)
{
    // ctl: [0..7] counts, [8..15] offsets, [16..23] cursor
    if (threadIdx.x == 0 && blockIdx.x == 0) {
        int acc = 0;
        for (int e = 0; e < 8; e++) {
            ctl[8 + e] = acc;
            acc += ctl[e];
            ctl[16 + e] = 0;
        }
    }
}

// ---------------- bucket fill ----------------
__global__ __launch_bounds__(256) void bucket_kernel(
    const int* __restrict__ topi, int* __restrict__ ctl,
    int* __restrict__ bucket_tok, int* __restrict__ tok_slot)
{
    int t = blockIdx.x * 256 + threadIdx.x;
    if (t >= T_TOK) return;
    #pragma unroll
    for (int k = 0; k < 2; k++) {
        int e = topi[2 * t + k];
        int pos = atomicAdd(&ctl[16 + e], 1);
        int idx = ctl[8 + e] + pos;
        bucket_tok[idx] = t;
        tok_slot[2 * t + k] = idx;
    }
}

// ---------------- weight convert + transpose (fp32 [K][N] -> bf16 [N][K]) ----------------
__global__ __launch_bounds__(256) void wconv_kernel(
    const float* __restrict__ w1, const float* __restrict__ w2,
    ushort* __restrict__ w1t, ushort* __restrict__ w2t)
{
    int mat = blockIdx.y;        // 0..7 = w1[e], 8..15 = w2[e]
    int e = mat & 7;
    bool isw2 = mat >= 8;
    int R = isw2 ? DF : DM;      // src rows (k)
    int Cc = isw2 ? DM : DF;     // src cols (n)
    const float* src = (isw2 ? w2 : w1) + (size_t)e * R * Cc;
    ushort* dst = (isw2 ? w2t : w1t) + (size_t)e * R * Cc;
    int tiles_c = Cc >> 5;
    int tc = blockIdx.x % tiles_c;
    int tr = blockIdx.x / tiles_c;
    int c0 = tc << 5, r0 = tr << 5;
    __shared__ float tile[32][33];
    int tx = threadIdx.x & 31, ty = threadIdx.x >> 5;
    #pragma unroll
    for (int j = 0; j < 4; j++) {
        int r = ty + j * 8;
        tile[r][tx] = src[(size_t)(r0 + r) * Cc + c0 + tx];
    }
    __syncthreads();
    #pragma unroll
    for (int j = 0; j < 4; j++) {
        int c = ty + j * 8;
        dst[(size_t)(c0 + c) * R + r0 + tx] = f2bf(tile[tx][c]);
    }
}

// ---------------- bucketed MFMA GEMM: C[M,N] = A[M,K] * Bt[N,K]^T ----------------
// 128x128 tile, BK=32, 4 waves, 16x16x32 bf16 MFMA, global_load_lds staging.
template<bool SILU, bool GATHER>
__global__ __launch_bounds__(256) void moe_gemm(
    const ushort* __restrict__ A, const ushort* __restrict__ Bt,
    ushort* __restrict__ C, const int* __restrict__ ctl,
    const int* __restrict__ bucket_tok, int K, int N)
{
    int e  = blockIdx.x >> 4;
    int mt = blockIdx.x & 15;
    int nt = blockIdx.y;
    int cnt = ctl[e];
    if (mt * 128 >= cnt) return;
    int off = ctl[8 + e];

    __shared__ ushort Al[128 * 32];
    __shared__ ushort Bl[128 * 32];

    int tid = threadIdx.x, lane = tid & 63, wv = tid >> 6;
    int kchunk = (lane & 3) * 8;          // ushort offset within 32-wide k slice

    const ushort* arow[2];
    #pragma unroll
    for (int i = 0; i < 2; i++) {
        int r = i * 64 + wv * 16 + (lane >> 2);
        int gr = mt * 128 + r;
        if (gr >= cnt) gr = cnt - 1;
        if (GATHER) arow[i] = A + (size_t)bucket_tok[off + gr] * K;
        else        arow[i] = A + (size_t)(off + gr) * K;
    }
    const ushort* brow[2];
    size_t bbase = (size_t)e * N * K;
    #pragma unroll
    for (int i = 0; i < 2; i++) {
        int n = nt * 128 + i * 64 + wv * 16 + (lane >> 2);
        brow[i] = Bt + bbase + (size_t)n * K;
    }

    f32x4 acc[4][4];
    #pragma unroll
    for (int m = 0; m < 4; m++)
        #pragma unroll
        for (int n = 0; n < 4; n++)
            acc[m][n] = (f32x4){0.f, 0.f, 0.f, 0.f};

    int wr = wv >> 1, wc = wv & 1;
    int l15 = lane & 15, kq = lane >> 4;

    for (int k0 = 0; k0 < K; k0 += 32) {
        #pragma unroll
        for (int i = 0; i < 2; i++) {
            __builtin_amdgcn_global_load_lds(
                (const __attribute__((address_space(1))) void*)(arow[i] + k0 + kchunk),
                (__attribute__((address_space(3))) void*)(&Al[(i * 64 + wv * 16) * 32 + lane * 8]),
                16, 0, 0);
            __builtin_amdgcn_global_load_lds(
                (const __attribute__((address_space(1))) void*)(brow[i] + k0 + kchunk),
                (__attribute__((address_space(3))) void*)(&Bl[(i * 64 + wv * 16) * 32 + lane * 8]),
                16, 0, 0);
        }
        __syncthreads();
        bf16x8 af[4], bfr[4];
        #pragma unroll
        for (int m = 0; m < 4; m++)
            af[m] = *(const bf16x8*)&Al[(wr * 64 + m * 16 + l15) * 32 + kq * 8];
        #pragma unroll
        for (int n = 0; n < 4; n++)
            bfr[n] = *(const bf16x8*)&Bl[(wc * 64 + n * 16 + l15) * 32 + kq * 8];
        #pragma unroll
        for (int m = 0; m < 4; m++)
            #pragma unroll
            for (int n = 0; n < 4; n++)
                acc[m][n] = __builtin_amdgcn_mfma_f32_16x16x32_bf16(af[m], bfr[n], acc[m][n], 0, 0, 0);
        __syncthreads();
    }

    // epilogue: row = (lane>>4)*4 + j, col = lane&15  (verified C/D mapping)
    #pragma unroll
    for (int m = 0; m < 4; m++) {
        #pragma unroll
        for (int n = 0; n < 4; n++) {
            #pragma unroll
            for (int j = 0; j < 4; j++) {
                int gr = mt * 128 + wr * 64 + m * 16 + kq * 4 + j;
                if (gr < cnt) {
                    float v = acc[m][n][j];
                    if (SILU) v = v / (1.0f + __expf(-v));
                    int col = nt * 128 + wc * 64 + n * 16 + l15;
                    C[(size_t)(off + gr) * N + col] = f2bf(v);
                }
            }
        }
    }
}

// ---------------- combine: out = residual + w0*y0 + w1*y1 ----------------
__global__ __launch_bounds__(256) void combine_kernel(
    const float* __restrict__ hs, const ushort* __restrict__ Yg,
    const float* __restrict__ topw, const int* __restrict__ tok_slot,
    float* __restrict__ out)
{
    int t = blockIdx.x, tid = threadIdx.x;
    int s0 = tok_slot[2 * t], s1 = tok_slot[2 * t + 1];
    float w0 = topw[2 * t], w1 = topw[2 * t + 1];
    const ushort* y0 = Yg + (size_t)s0 * DM;
    const ushort* y1 = Yg + (size_t)s1 * DM;
    const float* h = hs + (size_t)t * DM;
    float* o = out + (size_t)t * DM;
    #pragma unroll
    for (int i = 0; i < 3; i++) {
        int d = tid + i * 256;
        o[d] = h[d] + w0 * bf2f(y0[d]) + w1 * bf2f(y1[d]);
    }
}

extern "C" void kernel_launch(void* const* d_in, const int* in_sizes, int n_in,
                              void* d_out, int out_size, void* d_ws, size_t ws_size,
                              hipStream_t stream)
{
    const float* hs    = (const float*)d_in[0];
    const float* gamma = (const float*)d_in[1];
    const float* beta  = (const float*)d_in[2];
    const float* rw    = (const float*)d_in[3];
    const float* w1    = (const float*)d_in[4];
    const float* w2    = (const float*)d_in[5];
    float* out = (float*)d_out;
    char* ws = (char*)d_ws;

    size_t o = 0;
    auto alc = [&](size_t b) { size_t r = o; o += (b + 255) & ~255ULL; return r; };
    int*    ctl        = (int*)(ws + alc(256));                       // counts[8], offsets[8], cursor[8]
    float*  topw       = (float*)(ws + alc((size_t)T_TOK * 2 * 4));
    int*    topi       = (int*)(ws + alc((size_t)T_TOK * 2 * 4));
    int*    tok_slot   = (int*)(ws + alc((size_t)T_TOK * 2 * 4));
    int*    bucket_tok = (int*)(ws + alc((size_t)T_TOK * 2 * 4));
    ushort* xbf        = (ushort*)(ws + alc((size_t)T_TOK * DM * 2));
    ushort* w1t        = (ushort*)(ws + alc((size_t)NE * DF * DM * 2));
    ushort* w2t        = (ushort*)(ws + alc((size_t)NE * DF * DM * 2));
    ushort* Hg         = (ushort*)(ws + alc((size_t)T_TOK * 2 * DF * 2));
    ushort* Yg         = (ushort*)(ws + alc((size_t)T_TOK * 2 * DM * 2));

    hipMemsetAsync(ctl, 0, 256, stream);
    wconv_kernel<<<dim3(2304, 16), 256, 0, stream>>>(w1, w2, w1t, w2t);
    ln_router_kernel<<<T_TOK, 256, 0, stream>>>(hs, gamma, beta, rw, xbf, topw, topi, ctl);
    scan_kernel<<<1, 64, 0, stream>>>(ctl);
    bucket_kernel<<<8, 256, 0, stream>>>(topi, ctl, bucket_tok, tok_slot);
    moe_gemm<true, true><<<dim3(128, 24), 256, 0, stream>>>(xbf, w1t, Hg, ctl, bucket_tok, DM, DF);
    moe_gemm<false, false><<<dim3(128, 6), 256, 0, stream>>>(Hg, w2t, Yg, ctl, bucket_tok, DF, DM);
    combine_kernel<<<T_TOK, 256, 0, stream>>>(hs, Yg, topw, tok_slot, out);
}

// Round 2
// 222.836 us; speedup vs baseline: 1.5316x; 1.5316x over previous
//
#include <hip/hip_runtime.h>
#include <hip/hip_bf16.h>
#include <math.h>

#define T_TOK 2048
#define DM 768
#define DF 3072
#define NE 8

typedef __attribute__((ext_vector_type(4))) float f32x4;
typedef __attribute__((ext_vector_type(8))) short bf16x8;
typedef __attribute__((ext_vector_type(8))) unsigned short u16x8;

static __device__ __forceinline__ ushort f2bf(float f) {
    union { float f; unsigned u; } x; x.f = f;
    unsigned r = x.u + 0x7fff + ((x.u >> 16) & 1);
    return (ushort)(r >> 16);
}
static __device__ __forceinline__ float bf2f(ushort u) {
    union { unsigned u; float f; } x; x.u = ((unsigned)u) << 16; return x.f;
}

// ---------------- LN + router (top-2) ----------------
__global__ __launch_bounds__(256) void ln_router_kernel(
    const float* __restrict__ hs, const float* __restrict__ gamma,
    const float* __restrict__ beta, const float* __restrict__ rw,
    ushort* __restrict__ xbf, float* __restrict__ topw, int* __restrict__ topi,
    int* __restrict__ counts)
{
    int t = blockIdx.x;
    int tid = threadIdx.x;
    const float* row = hs + (size_t)t * DM;
    float v[3];
    v[0] = row[tid]; v[1] = row[tid + 256]; v[2] = row[tid + 512];
    float s  = v[0] + v[1] + v[2];
    float sq = v[0]*v[0] + v[1]*v[1] + v[2]*v[2];
    #pragma unroll
    for (int off = 32; off > 0; off >>= 1) {
        s  += __shfl_down(s, off);
        sq += __shfl_down(sq, off);
    }
    __shared__ float wsum[4], wsq[4];
    __shared__ float pl[4][8];
    int lane = tid & 63, wv = tid >> 6;
    if (lane == 0) { wsum[wv] = s; wsq[wv] = sq; }
    __syncthreads();
    float tot  = wsum[0] + wsum[1] + wsum[2] + wsum[3];
    float totq = wsq[0] + wsq[1] + wsq[2] + wsq[3];
    float mu = tot * (1.0f / 768.0f);
    float var = totq * (1.0f / 768.0f) - mu * mu;
    float rstd = rsqrtf(var + 1e-5f);

    float p[8];
    #pragma unroll
    for (int e = 0; e < 8; e++) p[e] = 0.f;
    #pragma unroll
    for (int i = 0; i < 3; i++) {
        int d = tid + i * 256;
        float yv = (v[i] - mu) * rstd * gamma[d] + beta[d];
        xbf[(size_t)t * DM + d] = f2bf(yv);
        const float* r8 = rw + (size_t)d * 8;
        #pragma unroll
        for (int e = 0; e < 8; e++) p[e] += yv * r8[e];
    }
    #pragma unroll
    for (int off = 32; off > 0; off >>= 1) {
        #pragma unroll
        for (int e = 0; e < 8; e++) p[e] += __shfl_down(p[e], off);
    }
    if (lane == 0) {
        #pragma unroll
        for (int e = 0; e < 8; e++) pl[wv][e] = p[e];
    }
    __syncthreads();
    if (tid == 0) {
        float lg[8];
        #pragma unroll
        for (int e = 0; e < 8; e++) lg[e] = pl[0][e] + pl[1][e] + pl[2][e] + pl[3][e];
        int i0 = 0; float l0 = lg[0];
        #pragma unroll
        for (int e = 1; e < 8; e++) if (lg[e] > l0) { l0 = lg[e]; i0 = e; }
        int i1 = -1; float l1 = -3.4e38f;
        #pragma unroll
        for (int e = 0; e < 8; e++) if (e != i0 && lg[e] > l1) { l1 = lg[e]; i1 = e; }
        float w0 = 1.0f / (1.0f + __expf(l1 - l0));
        topi[2 * t] = i0;  topi[2 * t + 1] = i1;
        topw[2 * t] = w0;  topw[2 * t + 1] = 1.0f - w0;
        atomicAdd(&counts[i0], 1);
        atomicAdd(&counts[i1], 1);
    }
}

// ---------------- scan (prefix over 8 counts) ----------------
__global__ void scan_kernel(int* __restrict__ ctl)
{
    if (threadIdx.x == 0 && blockIdx.x == 0) {
        int acc = 0;
        for (int e = 0; e < 8; e++) {
            ctl[8 + e] = acc;
            acc += ctl[e];
            ctl[16 + e] = 0;
        }
    }
}

// ---------------- bucket fill ----------------
__global__ __launch_bounds__(256) void bucket_kernel(
    const int* __restrict__ topi, int* __restrict__ ctl,
    int* __restrict__ bucket_tok, int* __restrict__ tok_slot)
{
    int t = blockIdx.x * 256 + threadIdx.x;
    if (t >= T_TOK) return;
    #pragma unroll
    for (int k = 0; k < 2; k++) {
        int e = topi[2 * t + k];
        int pos = atomicAdd(&ctl[16 + e], 1);
        int idx = ctl[8 + e] + pos;
        bucket_tok[idx] = t;
        tok_slot[2 * t + k] = idx;
    }
}

// ---------------- weight convert + transpose (fp32 [K][N] -> bf16 [N][K]) ----------------
// 64x64 tiles, float4 loads, ushort8 stores.
__global__ __launch_bounds__(256) void wconv_kernel(
    const float* __restrict__ w1, const float* __restrict__ w2,
    ushort* __restrict__ w1t, ushort* __restrict__ w2t)
{
    int mat = blockIdx.y;        // 0..7 = w1[e], 8..15 = w2[e]
    int e = mat & 7;
    bool isw2 = mat >= 8;
    int R = isw2 ? DF : DM;      // src rows (k)
    int Cc = isw2 ? DM : DF;     // src cols (n)
    const float* src = (isw2 ? w2 : w1) + (size_t)e * R * Cc;
    ushort* dst = (isw2 ? w2t : w1t) + (size_t)e * R * Cc;
    int tiles_c = Cc >> 6;
    int tc = blockIdx.x % tiles_c;
    int tr = blockIdx.x / tiles_c;
    int c0 = tc << 6, r0 = tr << 6;
    __shared__ float tile[64][65];
    int tx = threadIdx.x & 15, ty = threadIdx.x >> 4;
    #pragma unroll
    for (int j = 0; j < 4; j++) {
        int r = ty + j * 16;
        float4 v = *(const float4*)&src[(size_t)(r0 + r) * Cc + c0 + tx * 4];
        tile[r][tx*4+0] = v.x; tile[r][tx*4+1] = v.y;
        tile[r][tx*4+2] = v.z; tile[r][tx*4+3] = v.w;
    }
    __syncthreads();
    int n  = threadIdx.x >> 2;          // 0..63 (dst row = col of src)
    int kc = (threadIdx.x & 3) * 16;    // dst k chunk
    u16x8 a, b;
    #pragma unroll
    for (int q = 0; q < 8; q++) {
        a[q] = f2bf(tile[kc + q][n]);
        b[q] = f2bf(tile[kc + 8 + q][n]);
    }
    ushort* dp = &dst[(size_t)(c0 + n) * R + r0 + kc];
    *(u16x8*)dp = a;
    *(u16x8*)(dp + 8) = b;
}

// ---------------- bucketed MFMA GEMM: C[M,N] = A[M,K] * Bt[N,K]^T ----------------
// 128x128 tile, BK=32, 4 waves, double-buffered single-barrier K-loop.
// Block mapping: e = bid&7 (XCD-aligned), then mt inner / (nt,sk) outer for L2 reuse.
template<bool SILU, bool GATHER, int NT, int SPLITS>
__global__ __launch_bounds__(256) void moe_gemm(
    const ushort* __restrict__ A, const ushort* __restrict__ Bt,
    ushort* __restrict__ C, const int* __restrict__ ctl,
    const int* __restrict__ bucket_tok, int K, int N)
{
    int bid = blockIdx.x;
    int e = bid & 7;
    int j = bid >> 3;
    int mt = j & 15;
    int c = j >> 4;              // [0, NT*SPLITS)
    int nt = c % NT;
    int sk = c / NT;
    int cnt = ctl[e];
    if (mt * 128 >= cnt) return;
    int off = ctl[8 + e];
    const int Ks = K / SPLITS;
    int kbase = sk * Ks;

    __shared__ ushort Al[2][128 * 32];
    __shared__ ushort Bl[2][128 * 32];

    int tid = threadIdx.x, lane = tid & 63, wv = tid >> 6;
    int kchunk = (lane & 3) * 8;

    const ushort* aptr[2];
    #pragma unroll
    for (int i = 0; i < 2; i++) {
        int r = i * 64 + wv * 16 + (lane >> 2);
        int gr = mt * 128 + r;
        if (gr >= cnt) gr = cnt - 1;
        if (GATHER) aptr[i] = A + (size_t)bucket_tok[off + gr] * K;
        else        aptr[i] = A + (size_t)(off + gr) * K;
    }
    const ushort* bptr[2];
    size_t bbase = (size_t)e * N * K;
    #pragma unroll
    for (int i = 0; i < 2; i++) {
        int n = nt * 128 + i * 64 + wv * 16 + (lane >> 2);
        bptr[i] = Bt + bbase + (size_t)n * K;
    }

    f32x4 acc[4][4];
    #pragma unroll
    for (int m = 0; m < 4; m++)
        #pragma unroll
        for (int n = 0; n < 4; n++)
            acc[m][n] = (f32x4){0.f, 0.f, 0.f, 0.f};

    int wr = wv >> 1, wc = wv & 1;
    int l15 = lane & 15, kq = lane >> 4;
    int ldst = (wv * 16) * 32 + lane * 8;

    auto stage = [&](int buf, int k0) {
        #pragma unroll
        for (int i = 0; i < 2; i++) {
            __builtin_amdgcn_global_load_lds(
                (const __attribute__((address_space(1))) void*)(aptr[i] + k0 + kchunk),
                (__attribute__((address_space(3))) void*)(&Al[buf][i * 64 * 32 + ldst]),
                16, 0, 0);
            __builtin_amdgcn_global_load_lds(
                (const __attribute__((address_space(1))) void*)(bptr[i] + k0 + kchunk),
                (__attribute__((address_space(3))) void*)(&Bl[buf][i * 64 * 32 + ldst]),
                16, 0, 0);
        }
    };

    const int nk = Ks >> 5;
    stage(0, kbase);
    asm volatile("s_waitcnt vmcnt(0)" ::: "memory");
    __builtin_amdgcn_s_barrier();

    for (int ks = 0; ks < nk; ks++) {
        int cur = ks & 1;
        if (ks + 1 < nk) stage(cur ^ 1, kbase + (ks + 1) * 32);
        bf16x8 af[4], bfr[4];
        #pragma unroll
        for (int m = 0; m < 4; m++)
            af[m] = *(const bf16x8*)&Al[cur][(wr * 64 + m * 16 + l15) * 32 + kq * 8];
        #pragma unroll
        for (int n = 0; n < 4; n++)
            bfr[n] = *(const bf16x8*)&Bl[cur][(wc * 64 + n * 16 + l15) * 32 + kq * 8];
        __builtin_amdgcn_s_setprio(1);
        #pragma unroll
        for (int m = 0; m < 4; m++)
            #pragma unroll
            for (int n = 0; n < 4; n++)
                acc[m][n] = __builtin_amdgcn_mfma_f32_16x16x32_bf16(af[m], bfr[n], acc[m][n], 0, 0, 0);
        __builtin_amdgcn_s_setprio(0);
        asm volatile("s_waitcnt vmcnt(0) lgkmcnt(0)" ::: "memory");
        __builtin_amdgcn_s_barrier();
    }

    // epilogue: row = (lane>>4)*4 + j, col = lane&15
    #pragma unroll
    for (int m = 0; m < 4; m++) {
        #pragma unroll
        for (int n = 0; n < 4; n++) {
            #pragma unroll
            for (int jj = 0; jj < 4; jj++) {
                int gr = mt * 128 + wr * 64 + m * 16 + kq * 4 + jj;
                if (gr < cnt) {
                    float v = acc[m][n][jj];
                    if (SILU) v = v / (1.0f + __expf(-v));
                    int col = nt * 128 + wc * 64 + n * 16 + l15;
                    C[((size_t)sk * (T_TOK * 2) + off + gr) * N + col] = f2bf(v);
                }
            }
        }
    }
}

// ---------------- combine: out = residual + w0*sum_s y0_s + w1*sum_s y1_s ----------------
template<int SPLITS>
__global__ __launch_bounds__(256) void combine_kernel(
    const float* __restrict__ hs, const ushort* __restrict__ Yp,
    const float* __restrict__ topw, const int* __restrict__ tok_slot,
    float* __restrict__ out)
{
    int t = blockIdx.x, tid = threadIdx.x;
    int s0 = tok_slot[2 * t], s1 = tok_slot[2 * t + 1];
    float w0 = topw[2 * t], w1 = topw[2 * t + 1];
    const float* h = hs + (size_t)t * DM;
    float* o = out + (size_t)t * DM;
    #pragma unroll
    for (int i = 0; i < 3; i++) {
        int d = tid + i * 256;
        float y0 = 0.f, y1 = 0.f;
        #pragma unroll
        for (int s = 0; s < SPLITS; s++) {
            y0 += bf2f(Yp[((size_t)s * (T_TOK * 2) + s0) * DM + d]);
            y1 += bf2f(Yp[((size_t)s * (T_TOK * 2) + s1) * DM + d]);
        }
        o[d] = h[d] + w0 * y0 + w1 * y1;
    }
}

extern "C" void kernel_launch(void* const* d_in, const int* in_sizes, int n_in,
                              void* d_out, int out_size, void* d_ws, size_t ws_size,
                              hipStream_t stream)
{
    const float* hs    = (const float*)d_in[0];
    const float* gamma = (const float*)d_in[1];
    const float* beta  = (const float*)d_in[2];
    const float* rw    = (const float*)d_in[3];
    const float* w1    = (const float*)d_in[4];
    const float* w2    = (const float*)d_in[5];
    float* out = (float*)d_out;
    char* ws = (char*)d_ws;

    size_t o = 0;
    auto alc = [&](size_t b) { size_t r = o; o += (b + 255) & ~255ULL; return r; };
    int*    ctl        = (int*)(ws + alc(256));
    float*  topw       = (float*)(ws + alc((size_t)T_TOK * 2 * 4));
    int*    topi       = (int*)(ws + alc((size_t)T_TOK * 2 * 4));
    int*    tok_slot   = (int*)(ws + alc((size_t)T_TOK * 2 * 4));
    int*    bucket_tok = (int*)(ws + alc((size_t)T_TOK * 2 * 4));
    ushort* xbf        = (ushort*)(ws + alc((size_t)T_TOK * DM * 2));
    ushort* w1t        = (ushort*)(ws + alc((size_t)NE * DF * DM * 2));
    ushort* w2t        = (ushort*)(ws + alc((size_t)NE * DF * DM * 2));
    ushort* Hg         = (ushort*)(ws + alc((size_t)T_TOK * 2 * DF * 2));
    size_t yp_off      = alc((size_t)4 * T_TOK * 2 * DM * 2);   // laid out for 4 splits (last buffer)
    ushort* Yp         = (ushort*)(ws + yp_off);
    bool can_split     = (o <= ws_size);

    hipMemsetAsync(ctl, 0, 256, stream);
    wconv_kernel<<<dim3(576, 16), 256, 0, stream>>>(w1, w2, w1t, w2t);
    ln_router_kernel<<<T_TOK, 256, 0, stream>>>(hs, gamma, beta, rw, xbf, topw, topi, ctl);
    scan_kernel<<<1, 64, 0, stream>>>(ctl);
    bucket_kernel<<<8, 256, 0, stream>>>(topi, ctl, bucket_tok, tok_slot);

    moe_gemm<true, true, 24, 1><<<8 * 16 * 24, 256, 0, stream>>>(
        xbf, w1t, Hg, ctl, bucket_tok, DM, DF);

    if (can_split) {
        moe_gemm<false, false, 6, 4><<<8 * 16 * 6 * 4, 256, 0, stream>>>(
            Hg, w2t, Yp, ctl, bucket_tok, DF, DM);
        combine_kernel<4><<<T_TOK, 256, 0, stream>>>(hs, Yp, topw, tok_slot, out);
    } else {
        moe_gemm<false, false, 6, 1><<<8 * 16 * 6, 256, 0, stream>>>(
            Hg, w2t, Yp, ctl, bucket_tok, DF, DM);
        combine_kernel<1><<<T_TOK, 256, 0, stream>>>(hs, Yp, topw, tok_slot, out);
    }
}

// Round 3
// 220.345 us; speedup vs baseline: 1.5489x; 1.0113x over previous
//
#include <hip/hip_runtime.h>
#include <hip/hip_bf16.h>
#include <math.h>

#define T_TOK 2048
#define DM 768
#define DF 3072
#define NE 8

typedef __attribute__((ext_vector_type(4))) float f32x4;
typedef __attribute__((ext_vector_type(8))) short bf16x8;

static __device__ __forceinline__ ushort f2bf(float f) {
    union { float f; unsigned u; } x; x.f = f;
    unsigned r = x.u + 0x7fff + ((x.u >> 16) & 1);
    return (ushort)(r >> 16);
}
static __device__ __forceinline__ float bf2f(ushort u) {
    union { unsigned u; float f; } x; x.u = ((unsigned)u) << 16; return x.f;
}
static __device__ __forceinline__ unsigned pk2(float lo, float hi) {
    return (unsigned)f2bf(lo) | ((unsigned)f2bf(hi) << 16);
}

// ---------------- LN + router (top-2) ----------------
__global__ __launch_bounds__(256) void ln_router_kernel(
    const float* __restrict__ hs, const float* __restrict__ gamma,
    const float* __restrict__ beta, const float* __restrict__ rw,
    ushort* __restrict__ xbf, float* __restrict__ topw, int* __restrict__ topi,
    int* __restrict__ counts)
{
    int t = blockIdx.x;
    int tid = threadIdx.x;
    const float* row = hs + (size_t)t * DM;
    float v[3];
    v[0] = row[tid]; v[1] = row[tid + 256]; v[2] = row[tid + 512];
    float s  = v[0] + v[1] + v[2];
    float sq = v[0]*v[0] + v[1]*v[1] + v[2]*v[2];
    #pragma unroll
    for (int off = 32; off > 0; off >>= 1) {
        s  += __shfl_down(s, off);
        sq += __shfl_down(sq, off);
    }
    __shared__ float wsum[4], wsq[4];
    __shared__ float pl[4][8];
    int lane = tid & 63, wv = tid >> 6;
    if (lane == 0) { wsum[wv] = s; wsq[wv] = sq; }
    __syncthreads();
    float tot  = wsum[0] + wsum[1] + wsum[2] + wsum[3];
    float totq = wsq[0] + wsq[1] + wsq[2] + wsq[3];
    float mu = tot * (1.0f / 768.0f);
    float var = totq * (1.0f / 768.0f) - mu * mu;
    float rstd = rsqrtf(var + 1e-5f);

    float p[8];
    #pragma unroll
    for (int e = 0; e < 8; e++) p[e] = 0.f;
    #pragma unroll
    for (int i = 0; i < 3; i++) {
        int d = tid + i * 256;
        float yv = (v[i] - mu) * rstd * gamma[d] + beta[d];
        xbf[(size_t)t * DM + d] = f2bf(yv);
        const float* r8 = rw + (size_t)d * 8;
        #pragma unroll
        for (int e = 0; e < 8; e++) p[e] += yv * r8[e];
    }
    #pragma unroll
    for (int off = 32; off > 0; off >>= 1) {
        #pragma unroll
        for (int e = 0; e < 8; e++) p[e] += __shfl_down(p[e], off);
    }
    if (lane == 0) {
        #pragma unroll
        for (int e = 0; e < 8; e++) pl[wv][e] = p[e];
    }
    __syncthreads();
    if (tid == 0) {
        float lg[8];
        #pragma unroll
        for (int e = 0; e < 8; e++) lg[e] = pl[0][e] + pl[1][e] + pl[2][e] + pl[3][e];
        int i0 = 0; float l0 = lg[0];
        #pragma unroll
        for (int e = 1; e < 8; e++) if (lg[e] > l0) { l0 = lg[e]; i0 = e; }
        int i1 = -1; float l1 = -3.4e38f;
        #pragma unroll
        for (int e = 0; e < 8; e++) if (e != i0 && lg[e] > l1) { l1 = lg[e]; i1 = e; }
        float w0 = 1.0f / (1.0f + __expf(l1 - l0));
        topi[2 * t] = i0;  topi[2 * t + 1] = i1;
        topw[2 * t] = w0;  topw[2 * t + 1] = 1.0f - w0;
        atomicAdd(&counts[i0], 1);
        atomicAdd(&counts[i1], 1);
    }
}

// ---------------- bucket fill (offsets computed in-register) ----------------
__global__ __launch_bounds__(256) void bucket_kernel(
    const int* __restrict__ topi, int* __restrict__ ctl,
    int* __restrict__ bucket_tok, int* __restrict__ tok_slot)
{
    int t = blockIdx.x * 256 + threadIdx.x;
    if (t >= T_TOK) return;
    int offs[8]; int acc = 0;
    #pragma unroll
    for (int e = 0; e < 8; e++) { offs[e] = acc; acc += ctl[e]; }
    #pragma unroll
    for (int k = 0; k < 2; k++) {
        int e = topi[2 * t + k];
        int pos = atomicAdd(&ctl[16 + e], 1);
        int idx = offs[e] + pos;
        bucket_tok[idx] = t;
        tok_slot[2 * t + k] = idx;
    }
}

// ---------------- streaming weight pack: fp32 [K][N] -> u32 bf16-pair [K/2][N] ----------------
// out[k2][n] = bf16(W[2k2][n]) | bf16(W[2k2+1][n])<<16.  No transpose, no LDS.
__global__ __launch_bounds__(256) void wpack_kernel(
    const float* __restrict__ w1, const float* __restrict__ w2,
    unsigned* __restrict__ w1p, unsigned* __restrict__ w2p)
{
    const size_t MQ = (size_t)NE * DM * DF / 8;   // u32-quads per matrix
    size_t stride = (size_t)gridDim.x * 256;
    for (size_t i = (size_t)blockIdx.x * 256 + threadIdx.x; i < 2 * MQ; i += stride) {
        bool m2 = i >= MQ;
        size_t o = (m2 ? i - MQ : i) * 4;          // u32 index in matrix (4-aligned)
        int N = m2 ? DM : DF;
        size_t n = o % (size_t)N;
        const float* src = (m2 ? w2 : w1) + 2 * o - n;
        float4 a = *(const float4*)src;            // row 2*k2 (even k)
        float4 b = *(const float4*)(src + N);      // row 2*k2+1
        uint4 r;
        r.x = pk2(a.x, b.x); r.y = pk2(a.y, b.y);
        r.z = pk2(a.z, b.z); r.w = pk2(a.w, b.w);
        *(uint4*)((m2 ? w2p : w1p) + o) = r;
    }
}

// ---------------- bucketed MFMA GEMM: C[M,N] = A[M,K] * B[K,N], B pair-packed ----------------
// A: [M][K] bf16 (k-contiguous). Bp: [K/2][N] u32 (bf16 k-pairs).
// 128x128 tile, BK=32, 4 waves, double-buffered single-barrier K-loop.
// B LDS tile [16 rows][128 n] u32, XOR-swizzled col ^= ((row&7)<<2) via pre-swizzled source.
template<bool SILU, bool GATHER, int NT, int SPLITS>
__global__ __launch_bounds__(256) void moe_gemm(
    const ushort* __restrict__ A, const unsigned* __restrict__ Bp,
    ushort* __restrict__ C, const int* __restrict__ ctl,
    const int* __restrict__ bucket_tok, int K, int N)
{
    int bid = blockIdx.x;
    int e = bid & 7;
    int j = bid >> 3;
    int mt = j & 15;
    int c = j >> 4;
    int nt = c % NT;
    int sk = c / NT;
    int cnt = ctl[e];
    if (mt * 128 >= cnt) return;
    int off = 0;
    #pragma unroll
    for (int q = 0; q < 8; q++) if (q < e) off += ctl[q];
    const int Ks = K / SPLITS;
    int kbase = sk * Ks;

    __shared__ ushort Al[2][128 * 32];
    __shared__ unsigned Bl[2][16 * 128];

    int tid = threadIdx.x, lane = tid & 63, wv = tid >> 6;
    int kchunk = (lane & 3) * 8;

    const ushort* aptr[2];
    #pragma unroll
    for (int i = 0; i < 2; i++) {
        int r = i * 64 + wv * 16 + (lane >> 2);
        int gr = mt * 128 + r;
        if (gr >= cnt) gr = cnt - 1;
        if (GATHER) aptr[i] = A + (size_t)bucket_tok[off + gr] * K;
        else        aptr[i] = A + (size_t)(off + gr) * K;
    }
    // B staging geometry: instr g = wv*2+ii covers u32 rows 2g,2g+1 of the [16][128] tile.
    const unsigned* Bb = Bp + (size_t)e * ((size_t)N * (K / 2));
    int n0 = nt * 128;
    int brow2[2], bscol[2];
    #pragma unroll
    for (int ii = 0; ii < 2; ii++) {
        int g = wv * 2 + ii;
        int row2 = 2 * g + (lane >> 5);
        int col4 = 4 * (lane & 31);
        brow2[ii] = row2;
        bscol[ii] = col4 ^ ((row2 & 7) << 2);
    }

    f32x4 acc[4][4];
    #pragma unroll
    for (int m = 0; m < 4; m++)
        #pragma unroll
        for (int n = 0; n < 4; n++)
            acc[m][n] = (f32x4){0.f, 0.f, 0.f, 0.f};

    int wr = wv >> 1, wc = wv & 1;
    int l15 = lane & 15, kq = lane >> 4;
    int ldstA = (wv * 16) * 32 + lane * 8;
    int xk = (kq & 1) << 4;                  // bank-spread key bit for B reads

    auto stage = [&](int buf, int k0) {
        #pragma unroll
        for (int i = 0; i < 2; i++) {
            __builtin_amdgcn_global_load_lds(
                (const __attribute__((address_space(1))) void*)(aptr[i] + k0 + kchunk),
                (__attribute__((address_space(3))) void*)(&Al[buf][i * 64 * 32 + ldstA]),
                16, 0, 0);
        }
        int k2b = k0 >> 1;
        #pragma unroll
        for (int ii = 0; ii < 2; ii++) {
            int g = wv * 2 + ii;
            __builtin_amdgcn_global_load_lds(
                (const __attribute__((address_space(1))) void*)(Bb + (size_t)(k2b + brow2[ii]) * N + n0 + bscol[ii]),
                (__attribute__((address_space(3))) void*)(&Bl[buf][g * 256 + lane * 4]),
                16, 0, 0);
        }
    };

    const int nk = Ks >> 5;
    stage(0, kbase);
    asm volatile("s_waitcnt vmcnt(0)" ::: "memory");
    __builtin_amdgcn_s_barrier();

    for (int ks = 0; ks < nk; ks++) {
        int cur = ks & 1;
        if (ks + 1 < nk) stage(cur ^ 1, kbase + (ks + 1) * 32);
        bf16x8 af[4], bfr[4];
        #pragma unroll
        for (int m = 0; m < 4; m++)
            af[m] = *(const bf16x8*)&Al[cur][(wr * 64 + m * 16 + l15) * 32 + kq * 8];
        const unsigned* Blc = &Bl[cur][0];
        #pragma unroll
        for (int n = 0; n < 4; n++) {
            int ncol = wc * 64 + n * 16 + l15;
            union { uint4 u; bf16x8 h; } cvu;
            cvu.u.x = Blc[(kq * 4 + 0) * 128 + (ncol ^ (xk | 0))];
            cvu.u.y = Blc[(kq * 4 + 1) * 128 + (ncol ^ (xk | 4))];
            cvu.u.z = Blc[(kq * 4 + 2) * 128 + (ncol ^ (xk | 8))];
            cvu.u.w = Blc[(kq * 4 + 3) * 128 + (ncol ^ (xk | 12))];
            bfr[n] = cvu.h;
        }
        __builtin_amdgcn_s_setprio(1);
        #pragma unroll
        for (int m = 0; m < 4; m++)
            #pragma unroll
            for (int n = 0; n < 4; n++)
                acc[m][n] = __builtin_amdgcn_mfma_f32_16x16x32_bf16(af[m], bfr[n], acc[m][n], 0, 0, 0);
        __builtin_amdgcn_s_setprio(0);
        asm volatile("s_waitcnt vmcnt(0) lgkmcnt(0)" ::: "memory");
        __builtin_amdgcn_s_barrier();
    }

    // epilogue: row = (lane>>4)*4 + j, col = lane&15
    #pragma unroll
    for (int m = 0; m < 4; m++) {
        #pragma unroll
        for (int n = 0; n < 4; n++) {
            #pragma unroll
            for (int jj = 0; jj < 4; jj++) {
                int gr = mt * 128 + wr * 64 + m * 16 + kq * 4 + jj;
                if (gr < cnt) {
                    float v = acc[m][n][jj];
                    if (SILU) v = v / (1.0f + __expf(-v));
                    int col = nt * 128 + wc * 64 + n * 16 + l15;
                    C[((size_t)sk * (T_TOK * 2) + off + gr) * N + col] = f2bf(v);
                }
            }
        }
    }
}

// ---------------- combine: out = residual + w0*sum_s y0_s + w1*sum_s y1_s ----------------
template<int SPLITS>
__global__ __launch_bounds__(256) void combine_kernel(
    const float* __restrict__ hs, const ushort* __restrict__ Yp,
    const float* __restrict__ topw, const int* __restrict__ tok_slot,
    float* __restrict__ out)
{
    int t = blockIdx.x, tid = threadIdx.x;
    int s0 = tok_slot[2 * t], s1 = tok_slot[2 * t + 1];
    float w0 = topw[2 * t], w1 = topw[2 * t + 1];
    const float* h = hs + (size_t)t * DM;
    float* o = out + (size_t)t * DM;
    #pragma unroll
    for (int i = 0; i < 3; i++) {
        int d = tid + i * 256;
        float y0 = 0.f, y1 = 0.f;
        #pragma unroll
        for (int s = 0; s < SPLITS; s++) {
            y0 += bf2f(Yp[((size_t)s * (T_TOK * 2) + s0) * DM + d]);
            y1 += bf2f(Yp[((size_t)s * (T_TOK * 2) + s1) * DM + d]);
        }
        o[d] = h[d] + w0 * y0 + w1 * y1;
    }
}

extern "C" void kernel_launch(void* const* d_in, const int* in_sizes, int n_in,
                              void* d_out, int out_size, void* d_ws, size_t ws_size,
                              hipStream_t stream)
{
    const float* hs    = (const float*)d_in[0];
    const float* gamma = (const float*)d_in[1];
    const float* beta  = (const float*)d_in[2];
    const float* rw    = (const float*)d_in[3];
    const float* w1    = (const float*)d_in[4];
    const float* w2    = (const float*)d_in[5];
    float* out = (float*)d_out;
    char* ws = (char*)d_ws;

    size_t o = 0;
    auto alc = [&](size_t b) { size_t r = o; o += (b + 255) & ~255ULL; return r; };
    int*      ctl        = (int*)(ws + alc(256));
    float*    topw       = (float*)(ws + alc((size_t)T_TOK * 2 * 4));
    int*      topi       = (int*)(ws + alc((size_t)T_TOK * 2 * 4));
    int*      tok_slot   = (int*)(ws + alc((size_t)T_TOK * 2 * 4));
    int*      bucket_tok = (int*)(ws + alc((size_t)T_TOK * 2 * 4));
    ushort*   xbf        = (ushort*)(ws + alc((size_t)T_TOK * DM * 2));
    unsigned* w1p        = (unsigned*)(ws + alc((size_t)NE * DF * DM * 2));
    unsigned* w2p        = (unsigned*)(ws + alc((size_t)NE * DF * DM * 2));
    ushort*   Hg         = (ushort*)(ws + alc((size_t)T_TOK * 2 * DF * 2));
    size_t yp_off        = alc((size_t)4 * T_TOK * 2 * DM * 2);
    ushort*   Yp         = (ushort*)(ws + yp_off);
    bool can_split       = (o <= ws_size);

    hipMemsetAsync(ctl, 0, 256, stream);
    wpack_kernel<<<2048, 256, 0, stream>>>(w1, w2, w1p, w2p);
    ln_router_kernel<<<T_TOK, 256, 0, stream>>>(hs, gamma, beta, rw, xbf, topw, topi, ctl);
    bucket_kernel<<<8, 256, 0, stream>>>(topi, ctl, bucket_tok, tok_slot);

    moe_gemm<true, true, 24, 1><<<8 * 16 * 24, 256, 0, stream>>>(
        xbf, w1p, Hg, ctl, bucket_tok, DM, DF);

    if (can_split) {
        moe_gemm<false, false, 6, 4><<<8 * 16 * 6 * 4, 256, 0, stream>>>(
            Hg, w2p, Yp, ctl, bucket_tok, DF, DM);
        combine_kernel<4><<<T_TOK, 256, 0, stream>>>(hs, Yp, topw, tok_slot, out);
    } else {
        moe_gemm<false, false, 6, 1><<<8 * 16 * 6, 256, 0, stream>>>(
            Hg, w2p, Yp, ctl, bucket_tok, DF, DM);
        combine_kernel<1><<<T_TOK, 256, 0, stream>>>(hs, Yp, topw, tok_slot, out);
    }
}

// Round 4
// 212.285 us; speedup vs baseline: 1.6077x; 1.0380x over previous
//
#include <hip/hip_runtime.h>
#include <hip/hip_bf16.h>
#include <math.h>

#define T_TOK 2048
#define DM 768
#define DF 3072
#define NE 8

typedef __attribute__((ext_vector_type(4))) float f32x4;
typedef __attribute__((ext_vector_type(8))) short bf16x8;

static __device__ __forceinline__ ushort f2bf(float f) {
    union { float f; unsigned u; } x; x.f = f;
    unsigned r = x.u + 0x7fff + ((x.u >> 16) & 1);
    return (ushort)(r >> 16);
}
static __device__ __forceinline__ float bf2f(ushort u) {
    union { unsigned u; float f; } x; x.u = ((unsigned)u) << 16; return x.f;
}
static __device__ __forceinline__ unsigned pk2(float lo, float hi) {
    return (unsigned)f2bf(lo) | ((unsigned)f2bf(hi) << 16);
}

// ---------------- LN + router (top-2) ----------------
__global__ __launch_bounds__(256) void ln_router_kernel(
    const float* __restrict__ hs, const float* __restrict__ gamma,
    const float* __restrict__ beta, const float* __restrict__ rw,
    ushort* __restrict__ xbf, float* __restrict__ topw, int* __restrict__ topi,
    int* __restrict__ counts)
{
    int t = blockIdx.x;
    int tid = threadIdx.x;
    const float* row = hs + (size_t)t * DM;
    float v[3];
    v[0] = row[tid]; v[1] = row[tid + 256]; v[2] = row[tid + 512];
    float s  = v[0] + v[1] + v[2];
    float sq = v[0]*v[0] + v[1]*v[1] + v[2]*v[2];
    #pragma unroll
    for (int off = 32; off > 0; off >>= 1) {
        s  += __shfl_down(s, off);
        sq += __shfl_down(sq, off);
    }
    __shared__ float wsum[4], wsq[4];
    __shared__ float pl[4][8];
    int lane = tid & 63, wv = tid >> 6;
    if (lane == 0) { wsum[wv] = s; wsq[wv] = sq; }
    __syncthreads();
    float tot  = wsum[0] + wsum[1] + wsum[2] + wsum[3];
    float totq = wsq[0] + wsq[1] + wsq[2] + wsq[3];
    float mu = tot * (1.0f / 768.0f);
    float var = totq * (1.0f / 768.0f) - mu * mu;
    float rstd = rsqrtf(var + 1e-5f);

    float p[8];
    #pragma unroll
    for (int e = 0; e < 8; e++) p[e] = 0.f;
    #pragma unroll
    for (int i = 0; i < 3; i++) {
        int d = tid + i * 256;
        float yv = (v[i] - mu) * rstd * gamma[d] + beta[d];
        xbf[(size_t)t * DM + d] = f2bf(yv);
        const float* r8 = rw + (size_t)d * 8;
        #pragma unroll
        for (int e = 0; e < 8; e++) p[e] += yv * r8[e];
    }
    #pragma unroll
    for (int off = 32; off > 0; off >>= 1) {
        #pragma unroll
        for (int e = 0; e < 8; e++) p[e] += __shfl_down(p[e], off);
    }
    if (lane == 0) {
        #pragma unroll
        for (int e = 0; e < 8; e++) pl[wv][e] = p[e];
    }
    __syncthreads();
    if (tid == 0) {
        float lg[8];
        #pragma unroll
        for (int e = 0; e < 8; e++) lg[e] = pl[0][e] + pl[1][e] + pl[2][e] + pl[3][e];
        int i0 = 0; float l0 = lg[0];
        #pragma unroll
        for (int e = 1; e < 8; e++) if (lg[e] > l0) { l0 = lg[e]; i0 = e; }
        int i1 = -1; float l1 = -3.4e38f;
        #pragma unroll
        for (int e = 0; e < 8; e++) if (e != i0 && lg[e] > l1) { l1 = lg[e]; i1 = e; }
        float w0 = 1.0f / (1.0f + __expf(l1 - l0));
        topi[2 * t] = i0;  topi[2 * t + 1] = i1;
        topw[2 * t] = w0;  topw[2 * t + 1] = 1.0f - w0;
        atomicAdd(&counts[i0], 1);
        atomicAdd(&counts[i1], 1);
    }
}

// ---------------- bucket fill (offsets computed in-register) ----------------
__global__ __launch_bounds__(256) void bucket_kernel(
    const int* __restrict__ topi, int* __restrict__ ctl,
    int* __restrict__ bucket_tok, int* __restrict__ tok_slot)
{
    int t = blockIdx.x * 256 + threadIdx.x;
    if (t >= T_TOK) return;
    int offs[8]; int acc = 0;
    #pragma unroll
    for (int e = 0; e < 8; e++) { offs[e] = acc; acc += ctl[e]; }
    #pragma unroll
    for (int k = 0; k < 2; k++) {
        int e = topi[2 * t + k];
        int pos = atomicAdd(&ctl[16 + e], 1);
        int idx = offs[e] + pos;
        bucket_tok[idx] = t;
        tok_slot[2 * t + k] = idx;
    }
}

// ---------------- bucketed MFMA GEMM with FUSED fp32->bf16 weight convert ----------------
// C[M,N] = A[M,K] * W[K,N];  A: [M][K] bf16;  W: fp32 [E][K][N] (raw input weights).
// 128x128 tile, BK=32, 4 waves, double-buffered single-barrier K-loop.
// B staging: global fp32 -> regs -> pk2 -> swizzled ds_write (u32 bf16-pairs [16][128]).
// A staging: global_load_lds (linear).
template<bool SILU, bool GATHER, int NT, int SPLITS>
__global__ __launch_bounds__(256) void moe_gemm(
    const ushort* __restrict__ A, const float* __restrict__ W,
    ushort* __restrict__ C, const int* __restrict__ ctl,
    const int* __restrict__ bucket_tok, int K, int N)
{
    int bid = blockIdx.x;
    int e = bid & 7;
    int j = bid >> 3;
    int mt = j & 15;
    int c = j >> 4;
    int nt = c % NT;
    int sk = c / NT;
    int cnt = ctl[e];
    if (mt * 128 >= cnt) return;
    int off = 0;
    #pragma unroll
    for (int q = 0; q < 8; q++) if (q < e) off += ctl[q];
    const int Ks = K / SPLITS;
    int kbase = sk * Ks;

    __shared__ ushort Al[2][128 * 32];
    __shared__ unsigned Bl[2][16 * 128];

    int tid = threadIdx.x, lane = tid & 63, wv = tid >> 6;
    int kchunk = (lane & 3) * 8;

    const ushort* aptr[2];
    #pragma unroll
    for (int i = 0; i < 2; i++) {
        int r = i * 64 + wv * 16 + (lane >> 2);
        int gr = mt * 128 + r;
        if (gr >= cnt) gr = cnt - 1;
        if (GATHER) aptr[i] = A + (size_t)bucket_tok[off + gr] * K;
        else        aptr[i] = A + (size_t)(off + gr) * K;
    }

    const float* Wb = W + (size_t)e * ((size_t)K * N);
    int n0 = nt * 128;
    // B staging items: item = wv*128 + ii*64 + lane -> rp (k-pair row 0..15), cc (col-chunk 0..31)
    int rp_[2], cc_[2];
    #pragma unroll
    for (int ii = 0; ii < 2; ii++) {
        int item = wv * 128 + ii * 64 + lane;
        rp_[ii] = item >> 5;
        cc_[ii] = item & 31;
    }

    f32x4 acc[4][4];
    #pragma unroll
    for (int m = 0; m < 4; m++)
        #pragma unroll
        for (int n = 0; n < 4; n++)
            acc[m][n] = (f32x4){0.f, 0.f, 0.f, 0.f};

    int wr = wv >> 1, wc = wv & 1;
    int l15 = lane & 15, kq = lane >> 4;
    int ldstA = (wv * 16) * 32 + lane * 8;
    int xk = (kq & 1) << 4;

    float4 breg[2][2];

    auto stageA = [&](int buf, int k0) {
        #pragma unroll
        for (int i = 0; i < 2; i++) {
            __builtin_amdgcn_global_load_lds(
                (const __attribute__((address_space(1))) void*)(aptr[i] + k0 + kchunk),
                (__attribute__((address_space(3))) void*)(&Al[buf][i * 64 * 32 + ldstA]),
                16, 0, 0);
        }
    };
    auto bload = [&](int k0) {
        #pragma unroll
        for (int ii = 0; ii < 2; ii++) {
            const float* s = Wb + (size_t)(k0 + 2 * rp_[ii]) * N + n0 + 4 * cc_[ii];
            breg[ii][0] = *(const float4*)s;
            breg[ii][1] = *(const float4*)(s + N);
        }
    };
    auto bwrite = [&](int buf) {
        #pragma unroll
        for (int ii = 0; ii < 2; ii++) {
            uint4 r;
            r.x = pk2(breg[ii][0].x, breg[ii][1].x);
            r.y = pk2(breg[ii][0].y, breg[ii][1].y);
            r.z = pk2(breg[ii][0].z, breg[ii][1].z);
            r.w = pk2(breg[ii][0].w, breg[ii][1].w);
            *(uint4*)&Bl[buf][rp_[ii] * 128 + ((4 * cc_[ii]) ^ ((rp_[ii] & 7) << 2))] = r;
        }
    };

    const int nk = Ks >> 5;
    stageA(0, kbase);
    bload(kbase);
    asm volatile("s_waitcnt vmcnt(0)" ::: "memory");
    bwrite(0);
    asm volatile("s_waitcnt lgkmcnt(0)" ::: "memory");
    __builtin_amdgcn_s_barrier();

    for (int ks = 0; ks < nk; ks++) {
        int cur = ks & 1;
        bool more = (ks + 1 < nk);
        if (more) {
            stageA(cur ^ 1, kbase + (ks + 1) * 32);
            bload(kbase + (ks + 1) * 32);
        }
        bf16x8 af[4], bfr[4];
        #pragma unroll
        for (int m = 0; m < 4; m++)
            af[m] = *(const bf16x8*)&Al[cur][(wr * 64 + m * 16 + l15) * 32 + kq * 8];
        const unsigned* Blc = &Bl[cur][0];
        #pragma unroll
        for (int n = 0; n < 4; n++) {
            int ncol = wc * 64 + n * 16 + l15;
            union { uint4 u; bf16x8 h; } cvu;
            cvu.u.x = Blc[(kq * 4 + 0) * 128 + (ncol ^ (xk | 0))];
            cvu.u.y = Blc[(kq * 4 + 1) * 128 + (ncol ^ (xk | 4))];
            cvu.u.z = Blc[(kq * 4 + 2) * 128 + (ncol ^ (xk | 8))];
            cvu.u.w = Blc[(kq * 4 + 3) * 128 + (ncol ^ (xk | 12))];
            bfr[n] = cvu.h;
        }
        __builtin_amdgcn_s_setprio(1);
        #pragma unroll
        for (int m = 0; m < 4; m++)
            #pragma unroll
            for (int n = 0; n < 4; n++)
                acc[m][n] = __builtin_amdgcn_mfma_f32_16x16x32_bf16(af[m], bfr[n], acc[m][n], 0, 0, 0);
        __builtin_amdgcn_s_setprio(0);
        if (more) {
            asm volatile("s_waitcnt vmcnt(0)" ::: "memory");
            bwrite(cur ^ 1);
        }
        asm volatile("s_waitcnt vmcnt(0) lgkmcnt(0)" ::: "memory");
        __builtin_amdgcn_s_barrier();
    }

    // epilogue: row = (lane>>4)*4 + jj, col = lane&15
    #pragma unroll
    for (int m = 0; m < 4; m++) {
        #pragma unroll
        for (int n = 0; n < 4; n++) {
            #pragma unroll
            for (int jj = 0; jj < 4; jj++) {
                int gr = mt * 128 + wr * 64 + m * 16 + kq * 4 + jj;
                if (gr < cnt) {
                    float v = acc[m][n][jj];
                    if (SILU) v = v / (1.0f + __expf(-v));
                    int col = nt * 128 + wc * 64 + n * 16 + l15;
                    C[((size_t)sk * (T_TOK * 2) + off + gr) * N + col] = f2bf(v);
                }
            }
        }
    }
}

// ---------------- combine: out = residual + w0*sum_s y0_s + w1*sum_s y1_s ----------------
template<int SPLITS>
__global__ __launch_bounds__(256) void combine_kernel(
    const float* __restrict__ hs, const ushort* __restrict__ Yp,
    const float* __restrict__ topw, const int* __restrict__ tok_slot,
    float* __restrict__ out)
{
    int t = blockIdx.x, tid = threadIdx.x;
    int s0 = tok_slot[2 * t], s1 = tok_slot[2 * t + 1];
    float w0 = topw[2 * t], w1 = topw[2 * t + 1];
    const float* h = hs + (size_t)t * DM;
    float* o = out + (size_t)t * DM;
    #pragma unroll
    for (int i = 0; i < 3; i++) {
        int d = tid + i * 256;
        float y0 = 0.f, y1 = 0.f;
        #pragma unroll
        for (int s = 0; s < SPLITS; s++) {
            y0 += bf2f(Yp[((size_t)s * (T_TOK * 2) + s0) * DM + d]);
            y1 += bf2f(Yp[((size_t)s * (T_TOK * 2) + s1) * DM + d]);
        }
        o[d] = h[d] + w0 * y0 + w1 * y1;
    }
}

extern "C" void kernel_launch(void* const* d_in, const int* in_sizes, int n_in,
                              void* d_out, int out_size, void* d_ws, size_t ws_size,
                              hipStream_t stream)
{
    const float* hs    = (const float*)d_in[0];
    const float* gamma = (const float*)d_in[1];
    const float* beta  = (const float*)d_in[2];
    const float* rw    = (const float*)d_in[3];
    const float* w1    = (const float*)d_in[4];
    const float* w2    = (const float*)d_in[5];
    float* out = (float*)d_out;
    char* ws = (char*)d_ws;

    size_t o = 0;
    auto alc = [&](size_t b) { size_t r = o; o += (b + 255) & ~255ULL; return r; };
    int*      ctl        = (int*)(ws + alc(256));
    float*    topw       = (float*)(ws + alc((size_t)T_TOK * 2 * 4));
    int*      topi       = (int*)(ws + alc((size_t)T_TOK * 2 * 4));
    int*      tok_slot   = (int*)(ws + alc((size_t)T_TOK * 2 * 4));
    int*      bucket_tok = (int*)(ws + alc((size_t)T_TOK * 2 * 4));
    ushort*   xbf        = (ushort*)(ws + alc((size_t)T_TOK * DM * 2));
    ushort*   Hg         = (ushort*)(ws + alc((size_t)T_TOK * 2 * DF * 2));
    size_t yp_off        = alc((size_t)4 * T_TOK * 2 * DM * 2);
    ushort*   Yp         = (ushort*)(ws + yp_off);
    bool can_split       = (o <= ws_size);

    hipMemsetAsync(ctl, 0, 256, stream);
    ln_router_kernel<<<T_TOK, 256, 0, stream>>>(hs, gamma, beta, rw, xbf, topw, topi, ctl);
    bucket_kernel<<<8, 256, 0, stream>>>(topi, ctl, bucket_tok, tok_slot);

    moe_gemm<true, true, 24, 1><<<8 * 16 * 24, 256, 0, stream>>>(
        xbf, w1, Hg, ctl, bucket_tok, DM, DF);

    if (can_split) {
        moe_gemm<false, false, 6, 4><<<8 * 16 * 6 * 4, 256, 0, stream>>>(
            Hg, w2, Yp, ctl, bucket_tok, DF, DM);
        combine_kernel<4><<<T_TOK, 256, 0, stream>>>(hs, Yp, topw, tok_slot, out);
    } else {
        moe_gemm<false, false, 6, 1><<<8 * 16 * 6, 256, 0, stream>>>(
            Hg, w2, Yp, ctl, bucket_tok, DF, DM);
        combine_kernel<1><<<T_TOK, 256, 0, stream>>>(hs, Yp, topw, tok_slot, out);
    }
}